// Round 7
// baseline (432.952 us; speedup 1.0000x reference)
//
#include <hip/hip_runtime.h>
#include <hip/hip_fp16.h>
#include <math.h>

constexpr int Lq = 8, Cq = 16, Hq = 240, Wq = 480, Rq = 8, MIDq = 8, SEM = 4;
constexpr int HWq = Hq * Wq;

__device__ __forceinline__ float sigmoidf_(float v) { return 1.0f / (1.0f + expf(-v)); }

struct alignas(16) h8 { __half v[8]; };

// conv1: x (L,16,H,W) -> silu -> f1 (L,8,H,W), 3x3 SAME zero-pad. (R5 exact)
__global__ void k_conv1(const float* __restrict__ x, const float* __restrict__ w1,
                        const float* __restrict__ b1, float* __restrict__ f1) {
    int b = blockIdx.x;
    int l = b & 7, y = b >> 3;
    int t = threadIdx.x;
    if (t >= Wq / 4) return;
    int xi = t * 4;
    float acc[MIDq][4];
#pragma unroll
    for (int m = 0; m < MIDq; m++) {
        float bv = b1[m];
#pragma unroll
        for (int o = 0; o < 4; o++) acc[m][o] = bv;
    }
#pragma unroll 1
    for (int ic = 0; ic < Cq; ic++) {
        const float* xin = x + (size_t)(l * Cq + ic) * HWq;
        const float* wrow = w1 + ic * 9;
#pragma unroll
        for (int r = 0; r < 3; r++) {
            int yy = y + r - 1;
            if (yy < 0 || yy >= Hq) continue;
            const float* rp = xin + yy * Wq;
            float4 mid = *(const float4*)(rp + xi);
            float lft = (xi > 0) ? rp[xi - 1] : 0.f;
            float rgt = (xi + 4 < Wq) ? rp[xi + 4] : 0.f;
            float in6[6] = {lft, mid.x, mid.y, mid.z, mid.w, rgt};
#pragma unroll
            for (int m = 0; m < MIDq; m++) {
                const float* wp = wrow + m * (Cq * 9) + r * 3;
                float w0 = wp[0], w1v = wp[1], w2 = wp[2];
#pragma unroll
                for (int o = 0; o < 4; o++)
                    acc[m][o] = fmaf(w0, in6[o],
                                fmaf(w1v, in6[o + 1],
                                fmaf(w2, in6[o + 2], acc[m][o])));
            }
        }
    }
    size_t rowoff = (size_t)y * Wq + xi;
#pragma unroll
    for (int m = 0; m < MIDq; m++) {
        float4 v;
        float a0 = acc[m][0], a1 = acc[m][1], a2 = acc[m][2], a3 = acc[m][3];
        v.x = a0 * sigmoidf_(a0);
        v.y = a1 * sigmoidf_(a1);
        v.z = a2 * sigmoidf_(a2);
        v.w = a3 * sigmoidf_(a3);
        *(float4*)(f1 + (size_t)(l * MIDq + m) * HWq + rowoff) = v;
    }
}

// conv2: f1 (L,8,H,W) -> f (L,2,H,W), 3x3 SAME zero-pad. (R5 exact)
__global__ void k_conv2(const float* __restrict__ f1, const float* __restrict__ w2,
                        const float* __restrict__ b2, float* __restrict__ f) {
    int b = blockIdx.x;
    int l = b & 7, y = b >> 3;
    int t = threadIdx.x;
    if (t >= Wq / 4) return;
    int xi = t * 4;
    float acc[2][4];
#pragma unroll
    for (int m = 0; m < 2; m++) {
        float bv = b2[m];
#pragma unroll
        for (int o = 0; o < 4; o++) acc[m][o] = bv;
    }
#pragma unroll 1
    for (int ic = 0; ic < MIDq; ic++) {
        const float* fin = f1 + (size_t)(l * MIDq + ic) * HWq;
        const float* wrow = w2 + ic * 9;
#pragma unroll
        for (int r = 0; r < 3; r++) {
            int yy = y + r - 1;
            if (yy < 0 || yy >= Hq) continue;
            const float* rp = fin + yy * Wq;
            float4 mid = *(const float4*)(rp + xi);
            float lft = (xi > 0) ? rp[xi - 1] : 0.f;
            float rgt = (xi + 4 < Wq) ? rp[xi + 4] : 0.f;
            float in6[6] = {lft, mid.x, mid.y, mid.z, mid.w, rgt};
#pragma unroll
            for (int m = 0; m < 2; m++) {
                const float* wp = wrow + m * (MIDq * 9) + r * 3;
                float w0 = wp[0], w1v = wp[1], w2v = wp[2];
#pragma unroll
                for (int o = 0; o < 4; o++)
                    acc[m][o] = fmaf(w0, in6[o],
                                fmaf(w1v, in6[o + 1],
                                fmaf(w2v, in6[o + 2], acc[m][o])));
            }
        }
    }
    size_t rowoff = (size_t)y * Wq + xi;
#pragma unroll
    for (int m = 0; m < 2; m++) {
        float4 v = {acc[m][0], acc[m][1], acc[m][2], acc[m][3]};
        *(float4*)(f + (size_t)(l * 2 + m) * HWq + rowoff) = v;
    }
}

// sobel (wrap-x, edge-y) + metric + tanh -> flow (L,2,H,W) (R5 exact)
__global__ void k_flow(const float* __restrict__ f, float* __restrict__ flow) {
    int idx = blockIdx.x * blockDim.x + threadIdx.x;
    if (idx >= Lq * HWq) return;
    int l = idx / HWq, rem = idx % HWq, y = rem / Wq, x = rem % Wq;
    const float* phi = f + (size_t)(l * 2 + 0) * HWq;
    const float* psi = f + (size_t)(l * 2 + 1) * HWq;
    float ph[3][3], ps[3][3];
#pragma unroll
    for (int i = 0; i < 3; i++) {
        int yy = y + i - 1;
        yy = yy < 0 ? 0 : (yy >= Hq ? Hq - 1 : yy);
#pragma unroll
        for (int j = 0; j < 3; j++) {
            int xx = x + j - 1;
            xx = (xx + Wq) % Wq;
            ph[i][j] = phi[yy * Wq + xx];
            ps[i][j] = psi[yy * Wq + xx];
        }
    }
    float gxp = (ph[0][2] - ph[0][0]) + 2.f * (ph[1][2] - ph[1][0]) + (ph[2][2] - ph[2][0]);
    float gyp = (ph[2][0] + 2.f * ph[2][1] + ph[2][2]) - (ph[0][0] + 2.f * ph[0][1] + ph[0][2]);
    float gxs = (ps[0][2] - ps[0][0]) + 2.f * (ps[1][2] - ps[1][0]) + (ps[2][2] - ps[2][0]);
    float gys = (ps[2][0] + 2.f * ps[2][1] + ps[2][2]) - (ps[0][0] + 2.f * ps[0][1] + ps[0][2]);
    float latf = (float)(-M_PI * 0.5 + (double)y * (M_PI / (double)(Hq - 1)));
    float metric = (float)(1.0 / (cos((double)latf) + 1e-6));
    float u = gxp * metric - gys;
    float v = gyp + gxs * metric;
    flow[(size_t)(l * 2 + 0) * HWq + rem] = tanhf(u);
    flow[(size_t)(l * 2 + 1) * HWq + rem] = tanhf(v);
}

// one-time: h0 (C,H,W,R) fp32 -> hpack (H,W,C,R) fp16
__global__ void k_pack(const float* __restrict__ h0, h8* __restrict__ hp) {
    int px = blockIdx.x * 256 + threadIdx.x;
    const float4* h4 = (const float4*)h0;
#pragma unroll 1
    for (int c = 0; c < Cq; c++) {
        float4 a = h4[(size_t)(c * HWq + px) * 2];
        float4 b = h4[(size_t)(c * HWq + px) * 2 + 1];
        h8 o;
        o.v[0] = __float2half(a.x); o.v[1] = __float2half(a.y);
        o.v[2] = __float2half(a.z); o.v[3] = __float2half(a.w);
        o.v[4] = __float2half(b.x); o.v[5] = __float2half(b.y);
        o.v[6] = __float2half(b.z); o.v[7] = __float2half(b.w);
        hp[(size_t)px * Cq + c] = o;
    }
}

// warp + add x_t + mean over R + per-48px-chunk rowsum partials.
// h layout (H,W,C,R) fp16: 4 corners -> 4 contiguous 256B blocks (line reuse
// across the c-loop). 48 px/block (10 chunks per row, never crossing rows),
// 192 thr (4 thr/px, 4 c each). 2400 blocks -> deep gather TLP.
__global__ void k_warp(const h8* __restrict__ hin, h8* __restrict__ hout,
                       const float* __restrict__ flow_l, const float* __restrict__ xl,
                       const float* __restrict__ listT, int l,
                       float* __restrict__ xf, float* __restrict__ rows_part) {
    int tid = threadIdx.x;
    int pxl = tid >> 2;                 // 0..47
    int px = blockIdx.x * 48 + pxl;
    int csub = tid & 3;
    int y = px / Wq, x = px % Wq;
    float dt = listT[l];
    float u = flow_l[px];
    float v = flow_l[HWq + px];
    float gxn = x * (2.0f / (Wq - 1)) - 1.0f;
    float gyn = y * (2.0f / (Hq - 1)) - 1.0f;
    float gx = gxn - u * dt;
    float gy = gyn - v * dt;
    float xp = (gx + 1.0f) * (Wq * 0.5f) - 0.5f;
    float yp = (gy + 1.0f) * (Hq * 0.5f) - 0.5f;
    xp = fminf(fmaxf(xp, 0.0f), (float)(Wq - 1));
    yp = fminf(fmaxf(yp, 0.0f), (float)(Hq - 1));
    float x0f = floorf(xp), y0f = floorf(yp);
    float wx = xp - x0f, wy = yp - y0f;
    int x0 = (int)x0f, y0 = (int)y0f;
    int x1 = min(x0 + 1, Wq - 1), y1 = min(y0 + 1, Hq - 1);
    int i00 = (y0 * Wq + x0) * Cq, i01 = (y0 * Wq + x1) * Cq;
    int i10 = (y1 * Wq + x0) * Cq, i11 = (y1 * Wq + x1) * Cq;
    float w00 = (1.f - wx) * (1.f - wy), w01 = wx * (1.f - wy);
    float w10 = (1.f - wx) * wy, w11 = wx * wy;
    int c0 = csub * 4;
    float m4[4];
#pragma unroll
    for (int cc = 0; cc < 4; cc++) {
        int c = c0 + cc;
        h8 A = hin[i00 + c], B = hin[i01 + c], C = hin[i10 + c], D = hin[i11 + c];
        float xt = xl[(size_t)c * HWq + px];
        float ssum = 0.f;
        h8 o;
#pragma unroll
        for (int k = 0; k < 8; k++) {
            float r = w00 * __half2float(A.v[k]) + w01 * __half2float(B.v[k]) +
                      w10 * __half2float(C.v[k]) + w11 * __half2float(D.v[k]);
            ssum += r;
            o.v[k] = __float2half(r + xt);
        }
        hout[(size_t)px * Cq + c] = o;
        m4[cc] = ssum * 0.125f + xt;
    }
    float4 mv = {m4[0], m4[1], m4[2], m4[3]};
    *(float4*)(xf + (size_t)px * Cq + c0) = mv;
    // chunk rowsum partials: lds[16][48], then 16 threads serial-sum 48.
    __shared__ float lred[Cq][48];
#pragma unroll
    for (int cc = 0; cc < 4; cc++) lred[c0 + cc][pxl] = m4[cc];
    __syncthreads();
    if (tid < Cq) {
        float s = 0.f;
#pragma unroll
        for (int k = 0; k < 48; k++) s += lred[tid][k];
        rows_part[(size_t)blockIdx.x * Cq + tid] = s;   // blockIdx = y*10+chunk
    }
}

// gates: per row y, sum 10 chunk partials -> SE MLP -> gates[y][c]
__global__ void k_gate(const float* __restrict__ rows_part,
                       const float* __restrict__ sw1, const float* __restrict__ sb1,
                       const float* __restrict__ sw2, const float* __restrict__ sb2,
                       float* __restrict__ gates) {
    int y = blockIdx.x;
    int t = threadIdx.x;
    __shared__ float ym[Cq];
    __shared__ float z[SEM];
    if (t < Cq) {
        float s = 0.f;
#pragma unroll
        for (int k = 0; k < 10; k++) s += rows_part[(size_t)(y * 10 + k) * Cq + t];
        ym[t] = s * (1.0f / Wq);
    }
    __syncthreads();
    if (t < SEM) {
        float a = sb1[t];
#pragma unroll
        for (int i = 0; i < Cq; i++) a = fmaf(sw1[t * Cq + i], ym[i], a);
        z[t] = a * sigmoidf_(a);
    }
    __syncthreads();
    if (t < Cq) {
        float a = sb2[t];
#pragma unroll
        for (int m = 0; m < SEM; m++) a = fmaf(sw2[t * SEM + m], z[m], a);
        gates[y * Cq + t] = sigmoidf_(a);
    }
}

// scale: out[c][px] = xf[px][c] * gate[y][c]; LDS transpose, both sides coalesced.
// 64 px/block (px groups of 4 never straddle a row: 480 % 4 == 0).
__global__ void k_scale(const float* __restrict__ xf, const float* __restrict__ gates,
                        float* __restrict__ out_l) {
    __shared__ float lv[64 * Cq];
    int t = threadIdx.x;
    int base = blockIdx.x * 64;
    ((float4*)lv)[t] = ((const float4*)xf)[(size_t)blockIdx.x * 256 + t];
    __syncthreads();
    int c = t & 15;
    int pg = t >> 4;                    // 16 groups of 4 px
    int px = base + pg * 4;
    int y = px / Wq;
    float gv = gates[y * Cq + c];
    float4 o;
    o.x = lv[(pg * 4 + 0) * Cq + c] * gv;
    o.y = lv[(pg * 4 + 1) * Cq + c] * gv;
    o.z = lv[(pg * 4 + 2) * Cq + c] * gv;
    o.w = lv[(pg * 4 + 3) * Cq + c] * gv;
    *(float4*)(out_l + (size_t)c * HWq + px) = o;
}

extern "C" void kernel_launch(void* const* d_in, const int* in_sizes, int n_in,
                              void* d_out, int out_size, void* d_ws, size_t ws_size,
                              hipStream_t stream) {
    const float* x = (const float*)d_in[0];
    const float* h0 = (const float*)d_in[1];
    const float* listT = (const float*)d_in[2];
    const float* hw1 = (const float*)d_in[3];
    const float* hb1 = (const float*)d_in[4];
    const float* hw2 = (const float*)d_in[5];
    const float* hb2 = (const float*)d_in[6];
    const float* sw1 = (const float*)d_in[7];
    const float* sb1 = (const float*)d_in[8];
    const float* sw2 = (const float*)d_in[9];
    const float* sb2 = (const float*)d_in[10];
    float* out = (float*)d_out;
    char* ws = (char*)d_ws;

    size_t off = 0;
    float* flow = (float*)(ws + off); off += sizeof(float) * (size_t)Lq * 2 * HWq;
    float* f    = (float*)(ws + off); off += sizeof(float) * (size_t)Lq * 2 * HWq;
    float* f1   = (float*)(ws + off); off += sizeof(float) * (size_t)Lq * MIDq * HWq;
    h8* hA      = (h8*)(ws + off);    off += sizeof(h8) * (size_t)Cq * HWq;
    h8* hB      = (h8*)(ws + off);    off += sizeof(h8) * (size_t)Cq * HWq;
    float* xf   = (float*)(ws + off); off += sizeof(float) * (size_t)Cq * HWq;
    float* rp   = (float*)(ws + off); off += sizeof(float) * (size_t)(HWq / 48) * Cq;
    float* gts  = (float*)(ws + off); off += sizeof(float) * (size_t)Hq * Cq;

    k_conv1<<<Lq * Hq, 128, 0, stream>>>(x, hw1, hb1, f1);
    k_conv2<<<Lq * Hq, 128, 0, stream>>>(f1, hw2, hb2, f);
    k_flow<<<(Lq * HWq + 255) / 256, 256, 0, stream>>>(f, flow);
    k_pack<<<HWq / 256, 256, 0, stream>>>(h0, hA);

    h8* bufs[2] = {hA, hB};
    for (int l = 0; l < Lq; l++) {
        h8* hin = bufs[l & 1];
        h8* hout = bufs[(l + 1) & 1];
        k_warp<<<HWq / 48, 192, 0, stream>>>(hin, hout, flow + (size_t)l * 2 * HWq,
                                             x + (size_t)l * Cq * HWq, listT, l, xf, rp);
        k_gate<<<Hq, 64, 0, stream>>>(rp, sw1, sb1, sw2, sb2, gts);
        k_scale<<<HWq / 64, 256, 0, stream>>>(xf, gts, out + (size_t)l * Cq * HWq);
    }
}

// Round 8
// 361.119 us; speedup vs baseline: 1.1989x; 1.1989x over previous
//
#include <hip/hip_runtime.h>
#include <hip/hip_fp16.h>
#include <math.h>

constexpr int Lq = 8, Cq = 16, Hq = 240, Wq = 480, Rq = 8, MIDq = 8, SEM = 4;
constexpr int HWq = Hq * Wq;

__device__ __forceinline__ float sigmoidf_(float v) { return 1.0f / (1.0f + expf(-v)); }

struct alignas(16) h8 { __half v[8]; };

// conv1: x (L,16,H,W) -> silu -> f1 (L,8,H,W), 3x3 SAME zero-pad. (R5 exact)
__global__ void k_conv1(const float* __restrict__ x, const float* __restrict__ w1,
                        const float* __restrict__ b1, float* __restrict__ f1) {
    int b = blockIdx.x;
    int l = b & 7, y = b >> 3;
    int t = threadIdx.x;
    if (t >= Wq / 4) return;
    int xi = t * 4;
    float acc[MIDq][4];
#pragma unroll
    for (int m = 0; m < MIDq; m++) {
        float bv = b1[m];
#pragma unroll
        for (int o = 0; o < 4; o++) acc[m][o] = bv;
    }
#pragma unroll 1
    for (int ic = 0; ic < Cq; ic++) {
        const float* xin = x + (size_t)(l * Cq + ic) * HWq;
        const float* wrow = w1 + ic * 9;
#pragma unroll
        for (int r = 0; r < 3; r++) {
            int yy = y + r - 1;
            if (yy < 0 || yy >= Hq) continue;
            const float* rp = xin + yy * Wq;
            float4 mid = *(const float4*)(rp + xi);
            float lft = (xi > 0) ? rp[xi - 1] : 0.f;
            float rgt = (xi + 4 < Wq) ? rp[xi + 4] : 0.f;
            float in6[6] = {lft, mid.x, mid.y, mid.z, mid.w, rgt};
#pragma unroll
            for (int m = 0; m < MIDq; m++) {
                const float* wp = wrow + m * (Cq * 9) + r * 3;
                float w0 = wp[0], w1v = wp[1], w2 = wp[2];
#pragma unroll
                for (int o = 0; o < 4; o++)
                    acc[m][o] = fmaf(w0, in6[o],
                                fmaf(w1v, in6[o + 1],
                                fmaf(w2, in6[o + 2], acc[m][o])));
            }
        }
    }
    size_t rowoff = (size_t)y * Wq + xi;
#pragma unroll
    for (int m = 0; m < MIDq; m++) {
        float4 v;
        float a0 = acc[m][0], a1 = acc[m][1], a2 = acc[m][2], a3 = acc[m][3];
        v.x = a0 * sigmoidf_(a0);
        v.y = a1 * sigmoidf_(a1);
        v.z = a2 * sigmoidf_(a2);
        v.w = a3 * sigmoidf_(a3);
        *(float4*)(f1 + (size_t)(l * MIDq + m) * HWq + rowoff) = v;
    }
}

// conv2: f1 (L,8,H,W) -> f (L,2,H,W), 3x3 SAME zero-pad. (R5 exact)
__global__ void k_conv2(const float* __restrict__ f1, const float* __restrict__ w2,
                        const float* __restrict__ b2, float* __restrict__ f) {
    int b = blockIdx.x;
    int l = b & 7, y = b >> 3;
    int t = threadIdx.x;
    if (t >= Wq / 4) return;
    int xi = t * 4;
    float acc[2][4];
#pragma unroll
    for (int m = 0; m < 2; m++) {
        float bv = b2[m];
#pragma unroll
        for (int o = 0; o < 4; o++) acc[m][o] = bv;
    }
#pragma unroll 1
    for (int ic = 0; ic < MIDq; ic++) {
        const float* fin = f1 + (size_t)(l * MIDq + ic) * HWq;
        const float* wrow = w2 + ic * 9;
#pragma unroll
        for (int r = 0; r < 3; r++) {
            int yy = y + r - 1;
            if (yy < 0 || yy >= Hq) continue;
            const float* rp = fin + yy * Wq;
            float4 mid = *(const float4*)(rp + xi);
            float lft = (xi > 0) ? rp[xi - 1] : 0.f;
            float rgt = (xi + 4 < Wq) ? rp[xi + 4] : 0.f;
            float in6[6] = {lft, mid.x, mid.y, mid.z, mid.w, rgt};
#pragma unroll
            for (int m = 0; m < 2; m++) {
                const float* wp = wrow + m * (MIDq * 9) + r * 3;
                float w0 = wp[0], w1v = wp[1], w2v = wp[2];
#pragma unroll
                for (int o = 0; o < 4; o++)
                    acc[m][o] = fmaf(w0, in6[o],
                                fmaf(w1v, in6[o + 1],
                                fmaf(w2v, in6[o + 2], acc[m][o])));
            }
        }
    }
    size_t rowoff = (size_t)y * Wq + xi;
#pragma unroll
    for (int m = 0; m < 2; m++) {
        float4 v = {acc[m][0], acc[m][1], acc[m][2], acc[m][3]};
        *(float4*)(f + (size_t)(l * 2 + m) * HWq + rowoff) = v;
    }
}

// sobel (wrap-x, edge-y) + metric + tanh -> flow (L,2,H,W) (R5 exact)
__global__ void k_flow(const float* __restrict__ f, float* __restrict__ flow) {
    int idx = blockIdx.x * blockDim.x + threadIdx.x;
    if (idx >= Lq * HWq) return;
    int l = idx / HWq, rem = idx % HWq, y = rem / Wq, x = rem % Wq;
    const float* phi = f + (size_t)(l * 2 + 0) * HWq;
    const float* psi = f + (size_t)(l * 2 + 1) * HWq;
    float ph[3][3], ps[3][3];
#pragma unroll
    for (int i = 0; i < 3; i++) {
        int yy = y + i - 1;
        yy = yy < 0 ? 0 : (yy >= Hq ? Hq - 1 : yy);
#pragma unroll
        for (int j = 0; j < 3; j++) {
            int xx = x + j - 1;
            xx = (xx + Wq) % Wq;
            ph[i][j] = phi[yy * Wq + xx];
            ps[i][j] = psi[yy * Wq + xx];
        }
    }
    float gxp = (ph[0][2] - ph[0][0]) + 2.f * (ph[1][2] - ph[1][0]) + (ph[2][2] - ph[2][0]);
    float gyp = (ph[2][0] + 2.f * ph[2][1] + ph[2][2]) - (ph[0][0] + 2.f * ph[0][1] + ph[0][2]);
    float gxs = (ps[0][2] - ps[0][0]) + 2.f * (ps[1][2] - ps[1][0]) + (ps[2][2] - ps[2][0]);
    float gys = (ps[2][0] + 2.f * ps[2][1] + ps[2][2]) - (ps[0][0] + 2.f * ps[0][1] + ps[0][2]);
    float latf = (float)(-M_PI * 0.5 + (double)y * (M_PI / (double)(Hq - 1)));
    float metric = (float)(1.0 / (cos((double)latf) + 1e-6));
    float u = gxp * metric - gys;
    float v = gyp + gxs * metric;
    flow[(size_t)(l * 2 + 0) * HWq + rem] = tanhf(u);
    flow[(size_t)(l * 2 + 1) * HWq + rem] = tanhf(v);
}

// warp (bilinear, border clamp) + add x_t + mean over R + row sums.
// R5 structure (h fp16 (C,H,W,R), XCD-pinned (c,y) row blocks) with 2 adjacent
// px/thread: all 8 corner gathers issued before any consume -> 2x in-flight
// loads (R5 had 4, the stall). xf stored fp16 as half2.
template <typename TI>
__global__ __launch_bounds__(256) void k_warp(const TI* __restrict__ hin, h8* __restrict__ hout,
                       const float* __restrict__ flow_l, const float* __restrict__ xl,
                       const float* __restrict__ listT, int l,
                       __half* __restrict__ xf, float* __restrict__ rowsum) {
    int bid = blockIdx.x;
    int xcd = bid & 7;
    int local = bid >> 3;
    int c = xcd + 8 * (local / Hq);
    int y = local % Hq;
    int tid = threadIdx.x;
    int wave = tid >> 6, lane = tid & 63;
    bool act = tid < 240;
    int t2 = act ? tid : 239;
    int xa = t2 * 2, xb = xa + 1;
    float dt = listT[l];
    float gyn = y * (2.0f / (Hq - 1)) - 1.0f;
    const float* flu = flow_l + y * Wq;
    const float* flv = flow_l + HWq + y * Wq;
    const float* xrow = xl + (size_t)c * HWq + y * Wq;

    // coords for both px
    float2 uu = *(const float2*)(flu + xa);
    float2 vv = *(const float2*)(flv + xa);
    float2 xv = *(const float2*)(xrow + xa);
    int i00a, i01a, i10a, i11a, i00b, i01b, i10b, i11b;
    float w00a, w01a, w10a, w11a, w00b, w01b, w10b, w11b;
    {
        float gx = (xa * (2.0f / (Wq - 1)) - 1.0f) - uu.x * dt;
        float gy = gyn - vv.x * dt;
        float xp = fminf(fmaxf((gx + 1.0f) * (Wq * 0.5f) - 0.5f, 0.0f), (float)(Wq - 1));
        float yp = fminf(fmaxf((gy + 1.0f) * (Hq * 0.5f) - 0.5f, 0.0f), (float)(Hq - 1));
        float x0f = floorf(xp), y0f = floorf(yp);
        float wx = xp - x0f, wy = yp - y0f;
        int x0 = (int)x0f, y0 = (int)y0f;
        int x1 = min(x0 + 1, Wq - 1), y1 = min(y0 + 1, Hq - 1);
        i00a = (c * Hq + y0) * Wq + x0; i01a = (c * Hq + y0) * Wq + x1;
        i10a = (c * Hq + y1) * Wq + x0; i11a = (c * Hq + y1) * Wq + x1;
        w00a = (1.f - wx) * (1.f - wy); w01a = wx * (1.f - wy);
        w10a = (1.f - wx) * wy; w11a = wx * wy;
    }
    {
        float gx = (xb * (2.0f / (Wq - 1)) - 1.0f) - uu.y * dt;
        float gy = gyn - vv.y * dt;
        float xp = fminf(fmaxf((gx + 1.0f) * (Wq * 0.5f) - 0.5f, 0.0f), (float)(Wq - 1));
        float yp = fminf(fmaxf((gy + 1.0f) * (Hq * 0.5f) - 0.5f, 0.0f), (float)(Hq - 1));
        float x0f = floorf(xp), y0f = floorf(yp);
        float wx = xp - x0f, wy = yp - y0f;
        int x0 = (int)x0f, y0 = (int)y0f;
        int x1 = min(x0 + 1, Wq - 1), y1 = min(y0 + 1, Hq - 1);
        i00b = (c * Hq + y0) * Wq + x0; i01b = (c * Hq + y0) * Wq + x1;
        i10b = (c * Hq + y1) * Wq + x0; i11b = (c * Hq + y1) * Wq + x1;
        w00b = (1.f - wx) * (1.f - wy); w01b = wx * (1.f - wy);
        w10b = (1.f - wx) * wy; w11b = wx * wy;
    }

    float ra[8], rb[8];
    if constexpr (sizeof(TI) == 2) {
        const h8* hp = (const h8*)hin;
        // issue all 8 gathers, then consume
        h8 A0 = hp[i00a], B0 = hp[i01a], C0 = hp[i10a], D0 = hp[i11a];
        h8 A1 = hp[i00b], B1 = hp[i01b], C1 = hp[i10b], D1 = hp[i11b];
#pragma unroll
        for (int k = 0; k < 8; k++)
            ra[k] = w00a * __half2float(A0.v[k]) + w01a * __half2float(B0.v[k]) +
                    w10a * __half2float(C0.v[k]) + w11a * __half2float(D0.v[k]);
#pragma unroll
        for (int k = 0; k < 8; k++)
            rb[k] = w00b * __half2float(A1.v[k]) + w01b * __half2float(B1.v[k]) +
                    w10b * __half2float(C1.v[k]) + w11b * __half2float(D1.v[k]);
    } else {
        const float4* h4 = (const float4*)hin;
        float4 a0 = h4[i00a * 2], b0 = h4[i01a * 2], c0 = h4[i10a * 2], d0 = h4[i11a * 2];
        float4 a1 = h4[i00a * 2 + 1], b1 = h4[i01a * 2 + 1], c1 = h4[i10a * 2 + 1], d1 = h4[i11a * 2 + 1];
        ra[0] = w00a * a0.x + w01a * b0.x + w10a * c0.x + w11a * d0.x;
        ra[1] = w00a * a0.y + w01a * b0.y + w10a * c0.y + w11a * d0.y;
        ra[2] = w00a * a0.z + w01a * b0.z + w10a * c0.z + w11a * d0.z;
        ra[3] = w00a * a0.w + w01a * b0.w + w10a * c0.w + w11a * d0.w;
        ra[4] = w00a * a1.x + w01a * b1.x + w10a * c1.x + w11a * d1.x;
        ra[5] = w00a * a1.y + w01a * b1.y + w10a * c1.y + w11a * d1.y;
        ra[6] = w00a * a1.z + w01a * b1.z + w10a * c1.z + w11a * d1.z;
        ra[7] = w00a * a1.w + w01a * b1.w + w10a * c1.w + w11a * d1.w;
        float4 a2 = h4[i00b * 2], b2 = h4[i01b * 2], c2 = h4[i10b * 2], d2 = h4[i11b * 2];
        float4 a3 = h4[i00b * 2 + 1], b3 = h4[i01b * 2 + 1], c3 = h4[i10b * 2 + 1], d3 = h4[i11b * 2 + 1];
        rb[0] = w00b * a2.x + w01b * b2.x + w10b * c2.x + w11b * d2.x;
        rb[1] = w00b * a2.y + w01b * b2.y + w10b * c2.y + w11b * d2.y;
        rb[2] = w00b * a2.z + w01b * b2.z + w10b * c2.z + w11b * d2.z;
        rb[3] = w00b * a2.w + w01b * b2.w + w10b * c2.w + w11b * d2.w;
        rb[4] = w00b * a3.x + w01b * b3.x + w10b * c3.x + w11b * d3.x;
        rb[5] = w00b * a3.y + w01b * b3.y + w10b * c3.y + w11b * d3.y;
        rb[6] = w00b * a3.z + w01b * b3.z + w10b * c3.z + w11b * d3.z;
        rb[7] = w00b * a3.w + w01b * b3.w + w10b * c3.w + w11b * d3.w;
    }

    float ssa = ra[0] + ra[1] + ra[2] + ra[3] + ra[4] + ra[5] + ra[6] + ra[7];
    float ssb = rb[0] + rb[1] + rb[2] + rb[3] + rb[4] + rb[5] + rb[6] + rb[7];
    h8 oa, ob;
#pragma unroll
    for (int k = 0; k < 8; k++) {
        oa.v[k] = __float2half(ra[k] + xv.x);
        ob.v[k] = __float2half(rb[k] + xv.y);
    }
    float ma = ssa * 0.125f + xv.x;
    float mb = ssb * 0.125f + xv.y;
    if (act) {
        int po = (c * Hq + y) * Wq + xa;
        hout[po] = oa;
        hout[po + 1] = ob;
        __half2* xfrow = (__half2*)(xf + (size_t)(c * Hq + y) * Wq);
        xfrow[t2] = __floats2half2_rn(ma, mb);
    }
    float partial = act ? (ma + mb) : 0.f;
#pragma unroll
    for (int off = 32; off > 0; off >>= 1) partial += __shfl_down(partial, off, 64);
    __shared__ float sred[4];
    if (lane == 0) sred[wave] = partial;
    __syncthreads();
    if (tid == 0) rowsum[c * Hq + y] = sred[0] + sred[1] + sred[2] + sred[3];
}

// SE gate (recomputed per block from rowsums) + apply: out = xf * gate
__global__ void k_apply(const __half* __restrict__ xf, const float* __restrict__ rowsum,
                        const float* __restrict__ sw1, const float* __restrict__ sb1,
                        const float* __restrict__ sw2, const float* __restrict__ sb2,
                        float* __restrict__ out_l) {
    int c = blockIdx.x / Hq, y = blockIdx.x % Hq;
    float ym[Cq];
#pragma unroll
    for (int i = 0; i < Cq; i++) ym[i] = rowsum[i * Hq + y] * (1.0f / Wq);
    float z[SEM];
#pragma unroll
    for (int m = 0; m < SEM; m++) {
        float a = sb1[m];
#pragma unroll
        for (int i = 0; i < Cq; i++) a = fmaf(sw1[m * Cq + i], ym[i], a);
        z[m] = a * sigmoidf_(a);
    }
    float a = sb2[c];
#pragma unroll
    for (int m = 0; m < SEM; m++) a = fmaf(sw2[c * SEM + m], z[m], a);
    float gv = sigmoidf_(a);
    const __half2* s2 = (const __half2*)(xf + (size_t)(c * Hq + y) * Wq);
    float4* d4 = (float4*)(out_l + (size_t)(c * Hq + y) * Wq);
    int tid = threadIdx.x;
    if (tid < Wq / 4) {
        __half2 p0 = s2[tid * 2], p1 = s2[tid * 2 + 1];
        float2 f0 = __half22float2(p0), f1 = __half22float2(p1);
        float4 o = {f0.x * gv, f0.y * gv, f1.x * gv, f1.y * gv};
        d4[tid] = o;
    }
}

extern "C" void kernel_launch(void* const* d_in, const int* in_sizes, int n_in,
                              void* d_out, int out_size, void* d_ws, size_t ws_size,
                              hipStream_t stream) {
    const float* x = (const float*)d_in[0];
    const float* h0 = (const float*)d_in[1];
    const float* listT = (const float*)d_in[2];
    const float* hw1 = (const float*)d_in[3];
    const float* hb1 = (const float*)d_in[4];
    const float* hw2 = (const float*)d_in[5];
    const float* hb2 = (const float*)d_in[6];
    const float* sw1 = (const float*)d_in[7];
    const float* sb1 = (const float*)d_in[8];
    const float* sw2 = (const float*)d_in[9];
    const float* sb2 = (const float*)d_in[10];
    float* out = (float*)d_out;
    char* ws = (char*)d_ws;

    size_t off = 0;
    float* flow = (float*)(ws + off); off += sizeof(float) * (size_t)Lq * 2 * HWq;
    float* f    = (float*)(ws + off); off += sizeof(float) * (size_t)Lq * 2 * HWq;
    float* f1   = (float*)(ws + off); off += sizeof(float) * (size_t)Lq * MIDq * HWq;
    h8* hA      = (h8*)(ws + off);    off += sizeof(h8) * (size_t)Cq * HWq;
    h8* hB      = (h8*)(ws + off);    off += sizeof(h8) * (size_t)Cq * HWq;
    __half* xf  = (__half*)(ws + off); off += sizeof(__half) * (size_t)Cq * HWq;
    float* rows = (float*)(ws + off); off += sizeof(float) * (size_t)Cq * Hq;

    k_conv1<<<Lq * Hq, 128, 0, stream>>>(x, hw1, hb1, f1);
    k_conv2<<<Lq * Hq, 128, 0, stream>>>(f1, hw2, hb2, f);
    k_flow<<<(Lq * HWq + 255) / 256, 256, 0, stream>>>(f, flow);

    h8* bufs[2] = {hA, hB};
    for (int l = 0; l < Lq; l++) {
        h8* hout = bufs[l & 1];
        if (l == 0) {
            k_warp<float><<<Cq * Hq, 256, 0, stream>>>(h0, hout, flow,
                                                       x, listT, 0, xf, rows);
        } else {
            k_warp<__half><<<Cq * Hq, 256, 0, stream>>>((const __half*)bufs[(l - 1) & 1], hout,
                                                        flow + (size_t)l * 2 * HWq,
                                                        x + (size_t)l * Cq * HWq, listT, l, xf, rows);
        }
        k_apply<<<Cq * Hq, 128, 0, stream>>>(xf, rows, sw1, sb1, sw2, sb2,
                                             out + (size_t)l * Cq * HWq);
    }
}

// Round 9
// 187.862 us; speedup vs baseline: 2.3046x; 1.9223x over previous
//
#include <hip/hip_runtime.h>
#include <math.h>

constexpr int Lq = 8, Cq = 16, Hq = 240, Wq = 480, MIDq = 8, SEM = 4;
constexpr int HWq = Hq * Wq;
constexpr int CHUNK = 48;           // px per block in warp/out kernels
constexpr int NCH = Wq / CHUNK;     // 10 chunks per row

__device__ __forceinline__ float sigmoidf_(float v) { return 1.0f / (1.0f + expf(-v)); }

// conv1: x (L,16,H,W) -> silu -> f1 (L,8,H,W), 3x3 SAME zero-pad. (R5 exact)
__global__ void k_conv1(const float* __restrict__ x, const float* __restrict__ w1,
                        const float* __restrict__ b1, float* __restrict__ f1) {
    int b = blockIdx.x;
    int l = b & 7, y = b >> 3;
    int t = threadIdx.x;
    if (t >= Wq / 4) return;
    int xi = t * 4;
    float acc[MIDq][4];
#pragma unroll
    for (int m = 0; m < MIDq; m++) {
        float bv = b1[m];
#pragma unroll
        for (int o = 0; o < 4; o++) acc[m][o] = bv;
    }
#pragma unroll 1
    for (int ic = 0; ic < Cq; ic++) {
        const float* xin = x + (size_t)(l * Cq + ic) * HWq;
        const float* wrow = w1 + ic * 9;
#pragma unroll
        for (int r = 0; r < 3; r++) {
            int yy = y + r - 1;
            if (yy < 0 || yy >= Hq) continue;
            const float* rp = xin + yy * Wq;
            float4 mid = *(const float4*)(rp + xi);
            float lft = (xi > 0) ? rp[xi - 1] : 0.f;
            float rgt = (xi + 4 < Wq) ? rp[xi + 4] : 0.f;
            float in6[6] = {lft, mid.x, mid.y, mid.z, mid.w, rgt};
#pragma unroll
            for (int m = 0; m < MIDq; m++) {
                const float* wp = wrow + m * (Cq * 9) + r * 3;
                float w0 = wp[0], w1v = wp[1], w2 = wp[2];
#pragma unroll
                for (int o = 0; o < 4; o++)
                    acc[m][o] = fmaf(w0, in6[o],
                                fmaf(w1v, in6[o + 1],
                                fmaf(w2, in6[o + 2], acc[m][o])));
            }
        }
    }
    size_t rowoff = (size_t)y * Wq + xi;
#pragma unroll
    for (int m = 0; m < MIDq; m++) {
        float4 v;
        float a0 = acc[m][0], a1 = acc[m][1], a2 = acc[m][2], a3 = acc[m][3];
        v.x = a0 * sigmoidf_(a0);
        v.y = a1 * sigmoidf_(a1);
        v.z = a2 * sigmoidf_(a2);
        v.w = a3 * sigmoidf_(a3);
        *(float4*)(f1 + (size_t)(l * MIDq + m) * HWq + rowoff) = v;
    }
}

// conv2: f1 (L,8,H,W) -> f (L,2,H,W), 3x3 SAME zero-pad. (R5 exact)
__global__ void k_conv2(const float* __restrict__ f1, const float* __restrict__ w2,
                        const float* __restrict__ b2, float* __restrict__ f) {
    int b = blockIdx.x;
    int l = b & 7, y = b >> 3;
    int t = threadIdx.x;
    if (t >= Wq / 4) return;
    int xi = t * 4;
    float acc[2][4];
#pragma unroll
    for (int m = 0; m < 2; m++) {
        float bv = b2[m];
#pragma unroll
        for (int o = 0; o < 4; o++) acc[m][o] = bv;
    }
#pragma unroll 1
    for (int ic = 0; ic < MIDq; ic++) {
        const float* fin = f1 + (size_t)(l * MIDq + ic) * HWq;
        const float* wrow = w2 + ic * 9;
#pragma unroll
        for (int r = 0; r < 3; r++) {
            int yy = y + r - 1;
            if (yy < 0 || yy >= Hq) continue;
            const float* rp = fin + yy * Wq;
            float4 mid = *(const float4*)(rp + xi);
            float lft = (xi > 0) ? rp[xi - 1] : 0.f;
            float rgt = (xi + 4 < Wq) ? rp[xi + 4] : 0.f;
            float in6[6] = {lft, mid.x, mid.y, mid.z, mid.w, rgt};
#pragma unroll
            for (int m = 0; m < 2; m++) {
                const float* wp = wrow + m * (MIDq * 9) + r * 3;
                float w0 = wp[0], w1v = wp[1], w2v = wp[2];
#pragma unroll
                for (int o = 0; o < 4; o++)
                    acc[m][o] = fmaf(w0, in6[o],
                                fmaf(w1v, in6[o + 1],
                                fmaf(w2v, in6[o + 2], acc[m][o])));
            }
        }
    }
    size_t rowoff = (size_t)y * Wq + xi;
#pragma unroll
    for (int m = 0; m < 2; m++) {
        float4 v = {acc[m][0], acc[m][1], acc[m][2], acc[m][3]};
        *(float4*)(f + (size_t)(l * 2 + m) * HWq + rowoff) = v;
    }
}

// sobel (wrap-x, edge-y) + metric + tanh -> flow (L,2,H,W) (R5 exact)
__global__ void k_flow(const float* __restrict__ f, float* __restrict__ flow) {
    int idx = blockIdx.x * blockDim.x + threadIdx.x;
    if (idx >= Lq * HWq) return;
    int l = idx / HWq, rem = idx % HWq, y = rem / Wq, x = rem % Wq;
    const float* phi = f + (size_t)(l * 2 + 0) * HWq;
    const float* psi = f + (size_t)(l * 2 + 1) * HWq;
    float ph[3][3], ps[3][3];
#pragma unroll
    for (int i = 0; i < 3; i++) {
        int yy = y + i - 1;
        yy = yy < 0 ? 0 : (yy >= Hq ? Hq - 1 : yy);
#pragma unroll
        for (int j = 0; j < 3; j++) {
            int xx = x + j - 1;
            xx = (xx + Wq) % Wq;
            ph[i][j] = phi[yy * Wq + xx];
            ps[i][j] = psi[yy * Wq + xx];
        }
    }
    float gxp = (ph[0][2] - ph[0][0]) + 2.f * (ph[1][2] - ph[1][0]) + (ph[2][2] - ph[2][0]);
    float gyp = (ph[2][0] + 2.f * ph[2][1] + ph[2][2]) - (ph[0][0] + 2.f * ph[0][1] + ph[0][2]);
    float gxs = (ps[0][2] - ps[0][0]) + 2.f * (ps[1][2] - ps[1][0]) + (ps[2][2] - ps[2][0]);
    float gys = (ps[2][0] + 2.f * ps[2][1] + ps[2][2]) - (ps[0][0] + 2.f * ps[0][1] + ps[0][2]);
    float latf = (float)(-M_PI * 0.5 + (double)y * (M_PI / (double)(Hq - 1)));
    float metric = (float)(1.0 / (cos((double)latf) + 1e-6));
    float u = gxp * metric - gys;
    float v = gyp + gxs * metric;
    flow[(size_t)(l * 2 + 0) * HWq + rem] = tanhf(u);
    flow[(size_t)(l * 2 + 1) * HWq + rem] = tanhf(v);
}

// one-time: m0[px][c] = mean_r h0[c][px][r]   (h0: (C,H,W,R) fp32, R=8)
__global__ void k_m0(const float* __restrict__ h0, float* __restrict__ m0) {
    int px = blockIdx.x * 256 + threadIdx.x;
    const float4* h4 = (const float4*)h0;
    float4* mp = (float4*)(m0 + (size_t)px * Cq);
#pragma unroll
    for (int cq = 0; cq < 4; cq++) {
        float vals[4];
#pragma unroll
        for (int cc = 0; cc < 4; cc++) {
            int c = cq * 4 + cc;
            float4 a = h4[(size_t)(c * HWq + px) * 2];
            float4 b = h4[(size_t)(c * HWq + px) * 2 + 1];
            vals[cc] = (a.x + a.y + a.z + a.w + b.x + b.y + b.z + b.w) * 0.125f;
        }
        float4 o = {vals[0], vals[1], vals[2], vals[3]};
        mp[cq] = o;
    }
}

// warp of mean-state m (H,W,C) fp32: m_new = bilinear(m_old) + x_t.
// R-dim eliminated algebraically (warp linear + identical per r, x broadcast).
// 48 px/block, 4 thr/px (4 channels each, float4 per corner -> 4x 16B gathers,
// 64B contiguous per px across the 4 threads). x staged via LDS (coalesced).
// Deterministic per-chunk rowsum partials for the SE gate.
__global__ __launch_bounds__(192) void k_warp(const float* __restrict__ min_,
                       float* __restrict__ mout, const float* __restrict__ flow_l,
                       const float* __restrict__ xl, const float* __restrict__ listT,
                       int l, float* __restrict__ rows_part) {
    int b = blockIdx.x;
    int row = b / NCH;
    int chunk = b - row * NCH;
    int xbase = chunk * CHUNK;
    int t = threadIdx.x;
    int pxl = t >> 2, csub = t & 3;

    __shared__ float sx[Cq][CHUNK + 1];
    const float* xrowbase = xl + (size_t)row * Wq + xbase;
#pragma unroll
    for (int it = 0; it < 4; it++) {
        int fidx = it * 192 + t;
        int c = fidx / CHUNK;
        int p = fidx - c * CHUNK;
        sx[c][p] = xrowbase[(size_t)c * HWq + p];
    }
    __syncthreads();

    int x = xbase + pxl;
    float dt = listT[l];
    float u = flow_l[row * Wq + x];
    float v = flow_l[HWq + row * Wq + x];
    float gx = (x * (2.0f / (Wq - 1)) - 1.0f) - u * dt;
    float gy = (row * (2.0f / (Hq - 1)) - 1.0f) - v * dt;
    float xp = fminf(fmaxf((gx + 1.0f) * (Wq * 0.5f) - 0.5f, 0.0f), (float)(Wq - 1));
    float yp = fminf(fmaxf((gy + 1.0f) * (Hq * 0.5f) - 0.5f, 0.0f), (float)(Hq - 1));
    float x0f = floorf(xp), y0f = floorf(yp);
    float wx = xp - x0f, wy = yp - y0f;
    int x0 = (int)x0f, y0 = (int)y0f;
    int x1 = min(x0 + 1, Wq - 1), y1 = min(y0 + 1, Hq - 1);

    const float4* m4 = (const float4*)min_;
    float4 A = m4[(size_t)(y0 * Wq + x0) * 4 + csub];
    float4 B = m4[(size_t)(y0 * Wq + x1) * 4 + csub];
    float4 C = m4[(size_t)(y1 * Wq + x0) * 4 + csub];
    float4 D = m4[(size_t)(y1 * Wq + x1) * 4 + csub];
    float w00 = (1.f - wx) * (1.f - wy), w01 = wx * (1.f - wy);
    float w10 = (1.f - wx) * wy, w11 = wx * wy;
    int c0 = csub * 4;
    float r0 = w00 * A.x + w01 * B.x + w10 * C.x + w11 * D.x + sx[c0 + 0][pxl];
    float r1 = w00 * A.y + w01 * B.y + w10 * C.y + w11 * D.y + sx[c0 + 1][pxl];
    float r2 = w00 * A.z + w01 * B.z + w10 * C.z + w11 * D.z + sx[c0 + 2][pxl];
    float r3 = w00 * A.w + w01 * B.w + w10 * C.w + w11 * D.w + sx[c0 + 3][pxl];

    float4 o = {r0, r1, r2, r3};
    ((float4*)(mout + (size_t)(row * Wq + x) * Cq))[csub] = o;

    __shared__ float lred[Cq][CHUNK + 1];
    lred[c0 + 0][pxl] = r0;
    lred[c0 + 1][pxl] = r1;
    lred[c0 + 2][pxl] = r2;
    lred[c0 + 3][pxl] = r3;
    __syncthreads();
    if (t < Cq) {
        float s = 0.f;
#pragma unroll
        for (int k = 0; k < CHUNK; k++) s += lred[t][k];
        rows_part[(size_t)b * Cq + t] = s;
    }
}

// gates (recomputed per 48px chunk from rowsum partials) + transpose-store:
// out[c][y][x] = m[y][x][c] * gate[y][c]. Both global sides coalesced.
__global__ __launch_bounds__(192) void k_out(const float* __restrict__ m,
                       const float* __restrict__ rows_part,
                       const float* __restrict__ sw1, const float* __restrict__ sb1,
                       const float* __restrict__ sw2, const float* __restrict__ sb2,
                       float* __restrict__ out_l) {
    int b = blockIdx.x;
    int row = b / NCH;
    int chunk = b - row * NCH;
    int xbase = chunk * CHUNK;
    int t = threadIdx.x;
    int pxl = t >> 2, csub = t & 3;

    __shared__ float lm[CHUNK][Cq + 1];
    float4 vv = ((const float4*)(m + (size_t)(row * Wq + xbase + pxl) * Cq))[csub];
    lm[pxl][csub * 4 + 0] = vv.x;
    lm[pxl][csub * 4 + 1] = vv.y;
    lm[pxl][csub * 4 + 2] = vv.z;
    lm[pxl][csub * 4 + 3] = vv.w;

    __shared__ float ym[Cq];
    __shared__ float zz[SEM];
    __shared__ float gates[Cq];
    if (t < Cq) {
        float s = 0.f;
#pragma unroll
        for (int k = 0; k < NCH; k++) s += rows_part[(size_t)(row * NCH + k) * Cq + t];
        ym[t] = s * (1.0f / Wq);
    }
    __syncthreads();
    if (t < SEM) {
        float a = sb1[t];
#pragma unroll
        for (int i = 0; i < Cq; i++) a = fmaf(sw1[t * Cq + i], ym[i], a);
        zz[t] = a * sigmoidf_(a);
    }
    __syncthreads();
    if (t < Cq) {
        float a = sb2[t];
#pragma unroll
        for (int mm = 0; mm < SEM; mm++) a = fmaf(sw2[t * SEM + mm], zz[mm], a);
        gates[t] = sigmoidf_(a);
    }
    __syncthreads();

    int c = t / 12;            // 16 channels x 12 groups of 4 px
    int g = t - c * 12;
    float gv = gates[c];
    float4 o;
    o.x = lm[g * 4 + 0][c] * gv;
    o.y = lm[g * 4 + 1][c] * gv;
    o.z = lm[g * 4 + 2][c] * gv;
    o.w = lm[g * 4 + 3][c] * gv;
    *(float4*)(out_l + (size_t)c * HWq + row * Wq + xbase + g * 4) = o;
}

extern "C" void kernel_launch(void* const* d_in, const int* in_sizes, int n_in,
                              void* d_out, int out_size, void* d_ws, size_t ws_size,
                              hipStream_t stream) {
    const float* x = (const float*)d_in[0];
    const float* h0 = (const float*)d_in[1];
    const float* listT = (const float*)d_in[2];
    const float* hw1 = (const float*)d_in[3];
    const float* hb1 = (const float*)d_in[4];
    const float* hw2 = (const float*)d_in[5];
    const float* hb2 = (const float*)d_in[6];
    const float* sw1 = (const float*)d_in[7];
    const float* sb1 = (const float*)d_in[8];
    const float* sw2 = (const float*)d_in[9];
    const float* sb2 = (const float*)d_in[10];
    float* out = (float*)d_out;
    char* ws = (char*)d_ws;

    size_t off = 0;
    float* flow = (float*)(ws + off); off += sizeof(float) * (size_t)Lq * 2 * HWq;
    float* f    = (float*)(ws + off); off += sizeof(float) * (size_t)Lq * 2 * HWq;
    float* f1   = (float*)(ws + off); off += sizeof(float) * (size_t)Lq * MIDq * HWq;
    float* mA   = (float*)(ws + off); off += sizeof(float) * (size_t)HWq * Cq;
    float* mB   = (float*)(ws + off); off += sizeof(float) * (size_t)HWq * Cq;
    float* rp   = (float*)(ws + off); off += sizeof(float) * (size_t)(HWq / CHUNK) * Cq;

    k_conv1<<<Lq * Hq, 128, 0, stream>>>(x, hw1, hb1, f1);
    k_conv2<<<Lq * Hq, 128, 0, stream>>>(f1, hw2, hb2, f);
    k_flow<<<(Lq * HWq + 255) / 256, 256, 0, stream>>>(f, flow);
    k_m0<<<HWq / 256, 256, 0, stream>>>(h0, mA);

    float* bufs[2] = {mA, mB};
    for (int l = 0; l < Lq; l++) {
        float* min_ = bufs[l & 1];
        float* mout = bufs[(l + 1) & 1];
        k_warp<<<HWq / CHUNK, 192, 0, stream>>>(min_, mout, flow + (size_t)l * 2 * HWq,
                                                x + (size_t)l * Cq * HWq, listT, l, rp);
        k_out<<<HWq / CHUNK, 192, 0, stream>>>(mout, rp, sw1, sb1, sw2, sb2,
                                               out + (size_t)l * Cq * HWq);
    }
}

// Round 10
// 164.689 us; speedup vs baseline: 2.6289x; 1.1407x over previous
//
#include <hip/hip_runtime.h>
#include <math.h>

constexpr int Lq = 8, Cq = 16, Hq = 240, Wq = 480, MIDq = 8, SEM = 4;
constexpr int HWq = Hq * Wq;

__device__ __forceinline__ float sigmoidf_(float v) { return 1.0f / (1.0f + expf(-v)); }

// conv1: x (L,16,H,W) -> silu -> f1 (L,8,H,W), 3x3 SAME zero-pad.
// R10: unroll 2 on ic -> 2 load-groups in flight (was latency-serialized at 28 VGPR).
__global__ void k_conv1(const float* __restrict__ x, const float* __restrict__ w1,
                        const float* __restrict__ b1, float* __restrict__ f1) {
    int b = blockIdx.x;
    int l = b & 7, y = b >> 3;
    int t = threadIdx.x;
    if (t >= Wq / 4) return;
    int xi = t * 4;
    float acc[MIDq][4];
#pragma unroll
    for (int m = 0; m < MIDq; m++) {
        float bv = b1[m];
#pragma unroll
        for (int o = 0; o < 4; o++) acc[m][o] = bv;
    }
#pragma unroll 2
    for (int ic = 0; ic < Cq; ic++) {
        const float* xin = x + (size_t)(l * Cq + ic) * HWq;
        const float* wrow = w1 + ic * 9;
#pragma unroll
        for (int r = 0; r < 3; r++) {
            int yy = y + r - 1;
            if (yy < 0 || yy >= Hq) continue;
            const float* rp = xin + yy * Wq;
            float4 mid = *(const float4*)(rp + xi);
            float lft = (xi > 0) ? rp[xi - 1] : 0.f;
            float rgt = (xi + 4 < Wq) ? rp[xi + 4] : 0.f;
            float in6[6] = {lft, mid.x, mid.y, mid.z, mid.w, rgt};
#pragma unroll
            for (int m = 0; m < MIDq; m++) {
                const float* wp = wrow + m * (Cq * 9) + r * 3;
                float w0 = wp[0], w1v = wp[1], w2 = wp[2];
#pragma unroll
                for (int o = 0; o < 4; o++)
                    acc[m][o] = fmaf(w0, in6[o],
                                fmaf(w1v, in6[o + 1],
                                fmaf(w2, in6[o + 2], acc[m][o])));
            }
        }
    }
    size_t rowoff = (size_t)y * Wq + xi;
#pragma unroll
    for (int m = 0; m < MIDq; m++) {
        float4 v;
        float a0 = acc[m][0], a1 = acc[m][1], a2 = acc[m][2], a3 = acc[m][3];
        v.x = a0 * sigmoidf_(a0);
        v.y = a1 * sigmoidf_(a1);
        v.z = a2 * sigmoidf_(a2);
        v.w = a3 * sigmoidf_(a3);
        *(float4*)(f1 + (size_t)(l * MIDq + m) * HWq + rowoff) = v;
    }
}

// conv2: f1 (L,8,H,W) -> f (L,2,H,W), 3x3 SAME zero-pad. (unroll 2 likewise)
__global__ void k_conv2(const float* __restrict__ f1, const float* __restrict__ w2,
                        const float* __restrict__ b2, float* __restrict__ f) {
    int b = blockIdx.x;
    int l = b & 7, y = b >> 3;
    int t = threadIdx.x;
    if (t >= Wq / 4) return;
    int xi = t * 4;
    float acc[2][4];
#pragma unroll
    for (int m = 0; m < 2; m++) {
        float bv = b2[m];
#pragma unroll
        for (int o = 0; o < 4; o++) acc[m][o] = bv;
    }
#pragma unroll 2
    for (int ic = 0; ic < MIDq; ic++) {
        const float* fin = f1 + (size_t)(l * MIDq + ic) * HWq;
        const float* wrow = w2 + ic * 9;
#pragma unroll
        for (int r = 0; r < 3; r++) {
            int yy = y + r - 1;
            if (yy < 0 || yy >= Hq) continue;
            const float* rp = fin + yy * Wq;
            float4 mid = *(const float4*)(rp + xi);
            float lft = (xi > 0) ? rp[xi - 1] : 0.f;
            float rgt = (xi + 4 < Wq) ? rp[xi + 4] : 0.f;
            float in6[6] = {lft, mid.x, mid.y, mid.z, mid.w, rgt};
#pragma unroll
            for (int m = 0; m < 2; m++) {
                const float* wp = wrow + m * (MIDq * 9) + r * 3;
                float w0 = wp[0], w1v = wp[1], w2v = wp[2];
#pragma unroll
                for (int o = 0; o < 4; o++)
                    acc[m][o] = fmaf(w0, in6[o],
                                fmaf(w1v, in6[o + 1],
                                fmaf(w2v, in6[o + 2], acc[m][o])));
            }
        }
    }
    size_t rowoff = (size_t)y * Wq + xi;
#pragma unroll
    for (int m = 0; m < 2; m++) {
        float4 v = {acc[m][0], acc[m][1], acc[m][2], acc[m][3]};
        *(float4*)(f + (size_t)(l * 2 + m) * HWq + rowoff) = v;
    }
}

// sobel (wrap-x, edge-y) + metric + tanh -> flow (L,2,H,W) (R5 exact)
__global__ void k_flow(const float* __restrict__ f, float* __restrict__ flow) {
    int idx = blockIdx.x * blockDim.x + threadIdx.x;
    if (idx >= Lq * HWq) return;
    int l = idx / HWq, rem = idx % HWq, y = rem / Wq, x = rem % Wq;
    const float* phi = f + (size_t)(l * 2 + 0) * HWq;
    const float* psi = f + (size_t)(l * 2 + 1) * HWq;
    float ph[3][3], ps[3][3];
#pragma unroll
    for (int i = 0; i < 3; i++) {
        int yy = y + i - 1;
        yy = yy < 0 ? 0 : (yy >= Hq ? Hq - 1 : yy);
#pragma unroll
        for (int j = 0; j < 3; j++) {
            int xx = x + j - 1;
            xx = (xx + Wq) % Wq;
            ph[i][j] = phi[yy * Wq + xx];
            ps[i][j] = psi[yy * Wq + xx];
        }
    }
    float gxp = (ph[0][2] - ph[0][0]) + 2.f * (ph[1][2] - ph[1][0]) + (ph[2][2] - ph[2][0]);
    float gyp = (ph[2][0] + 2.f * ph[2][1] + ph[2][2]) - (ph[0][0] + 2.f * ph[0][1] + ph[0][2]);
    float gxs = (ps[0][2] - ps[0][0]) + 2.f * (ps[1][2] - ps[1][0]) + (ps[2][2] - ps[2][0]);
    float gys = (ps[2][0] + 2.f * ps[2][1] + ps[2][2]) - (ps[0][0] + 2.f * ps[0][1] + ps[0][2]);
    float latf = (float)(-M_PI * 0.5 + (double)y * (M_PI / (double)(Hq - 1)));
    float metric = (float)(1.0 / (cos((double)latf) + 1e-6));
    float u = gxp * metric - gys;
    float v = gyp + gxs * metric;
    flow[(size_t)(l * 2 + 0) * HWq + rem] = tanhf(u);
    flow[(size_t)(l * 2 + 1) * HWq + rem] = tanhf(v);
}

// one-time: m0[px][c] = mean_r h0[c][px][r]   (h0: (C,H,W,R) fp32, R=8)
__global__ void k_m0(const float* __restrict__ h0, float* __restrict__ m0) {
    int px = blockIdx.x * 256 + threadIdx.x;
    const float4* h4 = (const float4*)h0;
    float4* mp = (float4*)(m0 + (size_t)px * Cq);
#pragma unroll
    for (int cq = 0; cq < 4; cq++) {
        float vals[4];
#pragma unroll
        for (int cc = 0; cc < 4; cc++) {
            int c = cq * 4 + cc;
            float4 a = h4[(size_t)(c * HWq + px) * 2];
            float4 b = h4[(size_t)(c * HWq + px) * 2 + 1];
            vals[cc] = (a.x + a.y + a.z + a.w + b.x + b.y + b.z + b.w) * 0.125f;
        }
        float4 o = {vals[0], vals[1], vals[2], vals[3]};
        mp[cq] = o;
    }
}

// Fused scan step: warp(m) + x_t -> m_new (regs) -> global m write
//   -> LDS transpose -> per-wave channel rowsum -> SE gate -> out store.
// Block = one row y (grid 240), 1024 thr: 2 thr/px (8 ch each).
// m_new never re-read from global; k_out + rp eliminated.
__global__ __launch_bounds__(1024) void k_step(const float* __restrict__ min_,
                       float* __restrict__ mout, const float* __restrict__ flow_l,
                       const float* __restrict__ xl, const float* __restrict__ listT,
                       int l,
                       const float* __restrict__ sw1, const float* __restrict__ sb1,
                       const float* __restrict__ sw2, const float* __restrict__ sb2,
                       float* __restrict__ out_l) {
    constexpr int STR = 17;                     // LDS row stride (coprime 32)
    __shared__ float sm[Wq * STR];
    __shared__ float csum[Cq];
    __shared__ float zl[SEM];
    __shared__ float gl[Cq];

    int y = blockIdx.x;
    int t = threadIdx.x;
    int wave = t >> 6, lane = t & 63;
    bool act = t < 2 * Wq;
    int px = act ? (t >> 1) : (Wq - 1);
    int half = t & 1;
    int c0 = half * 8;

    float dt = listT[l];
    float mn[8];
    {
        float u = flow_l[y * Wq + px];
        float v = flow_l[HWq + y * Wq + px];
        float gx = (px * (2.0f / (Wq - 1)) - 1.0f) - u * dt;
        float gy = (y * (2.0f / (Hq - 1)) - 1.0f) - v * dt;
        float xp = fminf(fmaxf((gx + 1.0f) * (Wq * 0.5f) - 0.5f, 0.0f), (float)(Wq - 1));
        float yp = fminf(fmaxf((gy + 1.0f) * (Hq * 0.5f) - 0.5f, 0.0f), (float)(Hq - 1));
        float x0f = floorf(xp), y0f = floorf(yp);
        float wx = xp - x0f, wy = yp - y0f;
        int x0 = (int)x0f, y0 = (int)y0f;
        int x1 = min(x0 + 1, Wq - 1), y1 = min(y0 + 1, Hq - 1);
        const float4* m4 = (const float4*)min_;
        size_t b00 = (size_t)(y0 * Wq + x0) * 4 + (half * 2);
        size_t b01 = (size_t)(y0 * Wq + x1) * 4 + (half * 2);
        size_t b10 = (size_t)(y1 * Wq + x0) * 4 + (half * 2);
        size_t b11 = (size_t)(y1 * Wq + x1) * 4 + (half * 2);
        // 8 gathers all in flight
        float4 A0 = m4[b00], A1 = m4[b00 + 1];
        float4 B0 = m4[b01], B1 = m4[b01 + 1];
        float4 C0 = m4[b10], C1 = m4[b10 + 1];
        float4 D0 = m4[b11], D1 = m4[b11 + 1];
        float w00 = (1.f - wx) * (1.f - wy), w01 = wx * (1.f - wy);
        float w10 = (1.f - wx) * wy, w11 = wx * wy;
        const float* xb = xl + y * Wq + px;
        float xv[8];
#pragma unroll
        for (int j = 0; j < 8; j++) xv[j] = xb[(size_t)(c0 + j) * HWq];
        mn[0] = w00 * A0.x + w01 * B0.x + w10 * C0.x + w11 * D0.x + xv[0];
        mn[1] = w00 * A0.y + w01 * B0.y + w10 * C0.y + w11 * D0.y + xv[1];
        mn[2] = w00 * A0.z + w01 * B0.z + w10 * C0.z + w11 * D0.z + xv[2];
        mn[3] = w00 * A0.w + w01 * B0.w + w10 * C0.w + w11 * D0.w + xv[3];
        mn[4] = w00 * A1.x + w01 * B1.x + w10 * C1.x + w11 * D1.x + xv[4];
        mn[5] = w00 * A1.y + w01 * B1.y + w10 * C1.y + w11 * D1.y + xv[5];
        mn[6] = w00 * A1.z + w01 * B1.z + w10 * C1.z + w11 * D1.z + xv[6];
        mn[7] = w00 * A1.w + w01 * B1.w + w10 * C1.w + w11 * D1.w + xv[7];
    }
    if (act) {
        // m_new -> global (next step's gather source)
        float4* mo = (float4*)(mout + (size_t)(y * Wq + px) * Cq + c0);
        float4 o0 = {mn[0], mn[1], mn[2], mn[3]};
        float4 o1 = {mn[4], mn[5], mn[6], mn[7]};
        mo[0] = o0;
        mo[1] = o1;
        // LDS transpose for rowsum
#pragma unroll
        for (int j = 0; j < 8; j++) sm[px * STR + c0 + j] = mn[j];
    }
    __syncthreads();
    // wave w sums channel w across the row
    {
        float s = 0.f;
#pragma unroll
        for (int k = 0; k < 8; k++) {
            int p = k * 64 + lane;
            if (p < Wq) s += sm[p * STR + wave];
        }
#pragma unroll
        for (int off = 32; off > 0; off >>= 1) s += __shfl_down(s, off, 64);
        if (lane == 0) csum[wave] = s;
    }
    __syncthreads();
    if (t < SEM) {
        float a = sb1[t];
#pragma unroll
        for (int i = 0; i < Cq; i++) a = fmaf(sw1[t * Cq + i], csum[i] * (1.0f / Wq), a);
        zl[t] = a * sigmoidf_(a);
    }
    __syncthreads();
    if (t < Cq) {
        float a = sb2[t];
#pragma unroll
        for (int m = 0; m < SEM; m++) a = fmaf(sw2[t * SEM + m], zl[m], a);
        gl[t] = sigmoidf_(a);
    }
    __syncthreads();
    if (act) {
        float* ob = out_l + y * Wq + px;
#pragma unroll
        for (int j = 0; j < 8; j++)
            ob[(size_t)(c0 + j) * HWq] = mn[j] * gl[c0 + j];
    }
}

extern "C" void kernel_launch(void* const* d_in, const int* in_sizes, int n_in,
                              void* d_out, int out_size, void* d_ws, size_t ws_size,
                              hipStream_t stream) {
    const float* x = (const float*)d_in[0];
    const float* h0 = (const float*)d_in[1];
    const float* listT = (const float*)d_in[2];
    const float* hw1 = (const float*)d_in[3];
    const float* hb1 = (const float*)d_in[4];
    const float* hw2 = (const float*)d_in[5];
    const float* hb2 = (const float*)d_in[6];
    const float* sw1 = (const float*)d_in[7];
    const float* sb1 = (const float*)d_in[8];
    const float* sw2 = (const float*)d_in[9];
    const float* sb2 = (const float*)d_in[10];
    float* out = (float*)d_out;
    char* ws = (char*)d_ws;

    size_t off = 0;
    float* flow = (float*)(ws + off); off += sizeof(float) * (size_t)Lq * 2 * HWq;
    float* f    = (float*)(ws + off); off += sizeof(float) * (size_t)Lq * 2 * HWq;
    float* f1   = (float*)(ws + off); off += sizeof(float) * (size_t)Lq * MIDq * HWq;
    float* mA   = (float*)(ws + off); off += sizeof(float) * (size_t)HWq * Cq;
    float* mB   = (float*)(ws + off); off += sizeof(float) * (size_t)HWq * Cq;

    k_conv1<<<Lq * Hq, 128, 0, stream>>>(x, hw1, hb1, f1);
    k_conv2<<<Lq * Hq, 128, 0, stream>>>(f1, hw2, hb2, f);
    k_flow<<<(Lq * HWq + 255) / 256, 256, 0, stream>>>(f, flow);
    k_m0<<<HWq / 256, 256, 0, stream>>>(h0, mA);

    float* bufs[2] = {mA, mB};
    for (int l = 0; l < Lq; l++) {
        float* min_ = bufs[l & 1];
        float* mout = bufs[(l + 1) & 1];
        k_step<<<Hq, 1024, 0, stream>>>(min_, mout, flow + (size_t)l * 2 * HWq,
                                        x + (size_t)l * Cq * HWq, listT, l,
                                        sw1, sb1, sw2, sb2,
                                        out + (size_t)l * Cq * HWq);
    }
}